// Round 1
// baseline (428.671 us; speedup 1.0000x reference)
//
#include <hip/hip_runtime.h>

// Problem: B=16, N=128, F=64, K=128, C=3 (all fp32)
//   pa = S @ w[:F]  (+ b)     -> (B*N, K)
//   pb = S @ w[F:]            -> (B*N, K)
//   out[b,i,j,c,k] = (pa[b,i,k] + pb[b,j,k]) * dist[b,i,j,c]
// out = 402.65 MB fp32 -> HBM-write-bound. Target ~64 us write roofline.

#define BN   2048      // B*N rows
#define FF   64        // F
#define KK   128       // K

// Kernel A: per-row mini-GEMM. One block per row r (b*N+i), 128 threads = one k each.
// pa gets bias folded in. W columns (stride-128) are coalesced across k-threads;
// W (64 KB) is L2-resident after first block.
__global__ __launch_bounds__(128) void proj_kernel(
    const float* __restrict__ S,   // (BN, F)
    const float* __restrict__ W,   // (2F, K)
    const float* __restrict__ bias,// (K,)
    float* __restrict__ pa,        // (BN, K)  = S@W[:F] + bias
    float* __restrict__ pb)        // (BN, K)  = S@W[F:]
{
    __shared__ float s[FF];
    const int r = blockIdx.x;
    const int k = threadIdx.x;
    if (k < FF) s[k] = S[r * FF + k];
    __syncthreads();

    float acc_a = bias[k];
    float acc_b = 0.0f;
#pragma unroll
    for (int f = 0; f < FF; ++f) {
        const float sv = s[f];                 // LDS broadcast, conflict-free
        acc_a = fmaf(sv, W[f * KK + k], acc_a);
        acc_b = fmaf(sv, W[(f + FF) * KK + k], acc_b);
    }
    pa[r * KK + k] = acc_a;
    pb[r * KK + k] = acc_b;
}

// Kernel B: expansion. One block per (b,i) = 2048 blocks, 256 threads.
// Per block output = 128 j * 3 c * 128 k = 49152 floats = 12288 float4 (contiguous).
// Flat float4 index f: j = f/96, c = (f%96)/32, kq = f%32.
// Stores are 16B/lane fully coalesced; pb reads coalesced + L2-resident;
// dist read broadcasts across the 32 lanes sharing (j,c).
__global__ __launch_bounds__(256) void expand_kernel(
    const float* __restrict__ dist,  // (B, N, N, C)
    const float* __restrict__ pa,    // (BN, K) incl. bias
    const float* __restrict__ pb,    // (BN, K)
    float* __restrict__ out)         // (B, N, N, C, K)
{
    const int bi = blockIdx.x;          // b*128 + i
    const int b  = bi >> 7;
    const int tid = threadIdx.x;

    __shared__ float4 paB[KK / 4];      // pa[b,i,:] as 32 float4
    if (tid < KK / 4) paB[tid] = ((const float4*)pa)[bi * (KK / 4) + tid];
    __syncthreads();

    const float*  dist_bi = dist + (size_t)bi * 128 * 3;
    const float4* pb_b    = (const float4*)pb + (size_t)b * 128 * (KK / 4);
    float4*       out_bi  = (float4*)out + (size_t)bi * 12288;

#pragma unroll 4
    for (int f = tid; f < 12288; f += 256) {
        const int j  = f / 96;              // const-divisor -> magic mul
        const int r  = f - j * 96;
        const int c  = r >> 5;
        const int kq = r & 31;

        const float4 p = paB[kq];
        const float4 q = pb_b[j * 32 + kq];
        const float  d = dist_bi[j * 3 + c];

        float4 o;
        o.x = (p.x + q.x) * d;
        o.y = (p.y + q.y) * d;
        o.z = (p.z + q.z) * d;
        o.w = (p.w + q.w) * d;
        out_bi[f] = o;
    }
}

extern "C" void kernel_launch(void* const* d_in, const int* in_sizes, int n_in,
                              void* d_out, int out_size, void* d_ws, size_t ws_size,
                              hipStream_t stream) {
    const float* S    = (const float*)d_in[0];  // (16,128,64)
    const float* dist = (const float*)d_in[1];  // (16,128,128,3)
    const float* W    = (const float*)d_in[2];  // (128,128)
    const float* bias = (const float*)d_in[3];  // (128,)
    float* out = (float*)d_out;

    float* pa = (float*)d_ws;                   // BN*K floats = 1 MB
    float* pb = pa + (size_t)BN * KK;           // 1 MB

    proj_kernel<<<BN, 128, 0, stream>>>(S, W, bias, pa, pb);
    expand_kernel<<<BN, 256, 0, stream>>>(dist, pa, pb, out);
}